// Round 1
// baseline (1797.877 us; speedup 1.0000x reference)
//
#include <hip/hip_runtime.h>
#include <hip/hip_bf16.h>
#include <stdint.h>

// Problem constants
#define BB    8
#define HH    16
#define SS    640
#define STOK  512
#define STMN  128
#define HD    64
#define DIM   1024
#define NEGINF (-1e18f)

#define DOT4(A,B) ((A).x*(B).x + (A).y*(B).y + (A).z*(B).z + (A).w*(B).w)

// ---------------------------------------------------------------------------
// Kernel A: QKV projection.  x[5120][1024] @ qkv_w.T[1024][3072] + b
// 128x128 tile, BK=8, 8x8 per thread.  Scatter into q/k/v ws laid out
// [b][h][s][d] (q pre-scaled by 1/8).
// ---------------------------------------------------------------------------
__global__ __launch_bounds__(256) void gemm_qkv(
    const float* __restrict__ stok, const float* __restrict__ stm,
    const float* __restrict__ W, const float* __restrict__ bias,
    float* __restrict__ qws, float* __restrict__ kws, float* __restrict__ vws)
{
    __shared__ float As[8][128];
    __shared__ float Bs[8][128];
    const int t  = threadIdx.x;
    const int mt = blockIdx.x / 24, nt = blockIdx.x % 24;
    const int mb = mt * 128, nb = nt * 128;
    const int b  = mb / SS, sb = mb % SS;
    // each 128-row tile lies entirely in stok (sb<512) or stm (sb==512)
    const float* xbase = (sb >= STOK)
        ? (stm + ((size_t)b * STMN + (sb - STOK)) * DIM)
        : (stok + ((size_t)b * STOK + sb) * DIM);
    const int lr = t >> 1, lk = (t & 1) * 4;
    const float* ald = xbase + (size_t)lr * DIM + lk;
    const float* bld = W + (size_t)(nb + lr) * DIM + lk;
    const int ty = t >> 4, tx = t & 15;

    float acc[8][8];
#pragma unroll
    for (int i = 0; i < 8; ++i)
#pragma unroll
        for (int j = 0; j < 8; ++j) acc[i][j] = 0.f;

    for (int k0 = 0; k0 < DIM; k0 += 8) {
        float4 av = *reinterpret_cast<const float4*>(ald + k0);
        float4 bv = *reinterpret_cast<const float4*>(bld + k0);
        __syncthreads();
        As[lk + 0][lr] = av.x; As[lk + 1][lr] = av.y;
        As[lk + 2][lr] = av.z; As[lk + 3][lr] = av.w;
        Bs[lk + 0][lr] = bv.x; Bs[lk + 1][lr] = bv.y;
        Bs[lk + 2][lr] = bv.z; Bs[lk + 3][lr] = bv.w;
        __syncthreads();
#pragma unroll
        for (int kk = 0; kk < 8; ++kk) {
            float a[8], bbv[8];
            *reinterpret_cast<float4*>(a)     = *reinterpret_cast<float4*>(&As[kk][ty * 8]);
            *reinterpret_cast<float4*>(a + 4) = *reinterpret_cast<float4*>(&As[kk][ty * 8 + 4]);
            *reinterpret_cast<float4*>(bbv)     = *reinterpret_cast<float4*>(&Bs[kk][tx * 4]);
            *reinterpret_cast<float4*>(bbv + 4) = *reinterpret_cast<float4*>(&Bs[kk][64 + tx * 4]);
#pragma unroll
            for (int i = 0; i < 8; ++i)
#pragma unroll
                for (int j = 0; j < 8; ++j)
                    acc[i][j] = fmaf(a[i], bbv[j], acc[i][j]);
        }
    }
#pragma unroll
    for (int j = 0; j < 8; ++j) {
        int n = nb + (j < 4 ? tx * 4 + j : 64 + tx * 4 + (j - 4));
        float bia = bias[n];
        int sel = n >> 10, h = (n & 1023) >> 6, d = n & 63;
        float* dst = (sel == 0) ? qws : ((sel == 1) ? kws : vws);
        float scale = (sel == 0) ? 0.125f : 1.0f;
        size_t base = (((size_t)b * HH + h) * SS) * HD + d;
#pragma unroll
        for (int i = 0; i < 8; ++i) {
            int s = sb + ty * 8 + i;
            dst[base + (size_t)s * HD] = (acc[i][j] + bia) * scale;
        }
    }
}

// ---------------------------------------------------------------------------
// Kernel C: out projection.  ctx[5120][1024] @ out_w.T + out_b -> final
// ---------------------------------------------------------------------------
__global__ __launch_bounds__(256) void gemm_out(
    const float* __restrict__ X, const float* __restrict__ W,
    const float* __restrict__ bias, float* __restrict__ out)
{
    __shared__ float As[8][128];
    __shared__ float Bs[8][128];
    const int t  = threadIdx.x;
    const int mt = blockIdx.x / 8, nt = blockIdx.x % 8;
    const int mb = mt * 128, nb = nt * 128;
    const int lr = t >> 1, lk = (t & 1) * 4;
    const float* ald = X + (size_t)(mb + lr) * DIM + lk;
    const float* bld = W + (size_t)(nb + lr) * DIM + lk;
    const int ty = t >> 4, tx = t & 15;

    float acc[8][8];
#pragma unroll
    for (int i = 0; i < 8; ++i)
#pragma unroll
        for (int j = 0; j < 8; ++j) acc[i][j] = 0.f;

    for (int k0 = 0; k0 < DIM; k0 += 8) {
        float4 av = *reinterpret_cast<const float4*>(ald + k0);
        float4 bv = *reinterpret_cast<const float4*>(bld + k0);
        __syncthreads();
        As[lk + 0][lr] = av.x; As[lk + 1][lr] = av.y;
        As[lk + 2][lr] = av.z; As[lk + 3][lr] = av.w;
        Bs[lk + 0][lr] = bv.x; Bs[lk + 1][lr] = bv.y;
        Bs[lk + 2][lr] = bv.z; Bs[lk + 3][lr] = bv.w;
        __syncthreads();
#pragma unroll
        for (int kk = 0; kk < 8; ++kk) {
            float a[8], bbv[8];
            *reinterpret_cast<float4*>(a)     = *reinterpret_cast<float4*>(&As[kk][ty * 8]);
            *reinterpret_cast<float4*>(a + 4) = *reinterpret_cast<float4*>(&As[kk][ty * 8 + 4]);
            *reinterpret_cast<float4*>(bbv)     = *reinterpret_cast<float4*>(&Bs[kk][tx * 4]);
            *reinterpret_cast<float4*>(bbv + 4) = *reinterpret_cast<float4*>(&Bs[kk][64 + tx * 4]);
#pragma unroll
            for (int i = 0; i < 8; ++i)
#pragma unroll
                for (int j = 0; j < 8; ++j)
                    acc[i][j] = fmaf(a[i], bbv[j], acc[i][j]);
        }
    }
#pragma unroll
    for (int j = 0; j < 8; ++j) {
        int n = nb + (j < 4 ? tx * 4 + j : 64 + tx * 4 + (j - 4));
        float bia = bias[n];
#pragma unroll
        for (int i = 0; i < 8; ++i) {
            int m = mb + ty * 8 + i;
            out[(size_t)m * DIM + n] = acc[i][j] + bia;
        }
    }
}

// ---------------------------------------------------------------------------
// Kernel B: fused attention.  One block = one (b,h) and 8 query rows.
// Phases: load q -> qrel tables -> scores (5 K-tiles of 128) -> softmax ->
// attn write -> PV (5 V-tiles) -> rel-v bins -> rel-v matmul -> ctx write.
// ---------------------------------------------------------------------------
__global__ __launch_bounds__(256) void attn_kernel(
    const float* __restrict__ qws, const float* __restrict__ kws,
    const float* __restrict__ vws,
    const uint8_t* __restrict__ mtok, const uint8_t* __restrict__ mstm,
    const float* __restrict__ relk, const float* __restrict__ relv,
    const float* __restrict__ smk,  const float* __restrict__ smv,
    float* __restrict__ attn_out, float* __restrict__ ctx)
{
    __shared__ __align__(16) float s_lds[15152];
    float* sc  = s_lds;            // [8][644]   scores / probs
    float* kvb = s_lds + 5152;     // [128][68]  K/V tile; later relv tables
    float* qsb = s_lds + 13856;    // [8][64]    q rows; later reduce scratch
    float* wst = s_lds + 14368;    // [8][65]    qrel_k stok -> wbin stok
    float* wsm = s_lds + 14888;    // [8][33]    qrel_k stm  -> wbin stm

    const int t   = threadIdx.x;
    const int blk = blockIdx.x;
    const int qt  = blk % 80;
    const int bh  = blk / 80;
    const int b   = bh >> 4;
    const int h   = bh & 15;
    const int qbase = qt * 8;
    const bool q_stm = (qbase >= STOK);
    const size_t bh_off = (size_t)bh * (SS * HD);

    // P0: load 8 q rows (pre-scaled by kernel A)
    if (t < 128) {
        int row = t >> 4, c = t & 15;
        *reinterpret_cast<float4*>(&qsb[row * 64 + c * 4]) =
            *reinterpret_cast<const float4*>(&qws[bh_off + (size_t)(qbase + row) * HD + c * 4]);
    }
    __syncthreads();

    // P0b: qrel tables  qrel[i][v] = q_i . rel_emb_k[v]
    if (!q_stm) {
        for (int w = t; w < 8 * 65; w += 256) {
            int i = w / 65, v = w - i * 65;
            float a = 0.f;
#pragma unroll
            for (int dc = 0; dc < 16; ++dc) {
                float4 qv = *reinterpret_cast<float4*>(&qsb[i * 64 + dc * 4]);
                float4 rv = *reinterpret_cast<const float4*>(&relk[(size_t)v * 64 + dc * 4]);
                a += DOT4(qv, rv);
            }
            wst[w] = a;
        }
    } else {
        for (int w = t; w < 8 * 33; w += 256) {
            int i = w / 33, v = w - i * 33;
            float a = 0.f;
#pragma unroll
            for (int dc = 0; dc < 16; ++dc) {
                float4 qv = *reinterpret_cast<float4*>(&qsb[i * 64 + dc * 4]);
                float4 rv = *reinterpret_cast<const float4*>(&smk[(size_t)v * 64 + dc * 4]);
                a += DOT4(qv, rv);
            }
            wsm[w] = a;
        }
    }
    __syncthreads();

    // P1: scores.  thread -> rows {p,p+4}, keys {s,s+64} of a 128-key tile
    const int p_ = t >> 6;
    const int s_ = t & 63;
    const int r0 = p_, r1 = p_ + 4;

    auto handle = [&](int row, int gk, float val) {
        int gq = qbase + row;
        if (!q_stm) {
            if (gk < STOK) {
                int dlt = gk - gq;
                dlt = dlt < -32 ? -32 : (dlt > 32 ? 32 : dlt);
                val += wst[row * 65 + dlt + 32];
            }
        } else {
            if (gk < STOK) {
                val = NEGINF;           // stm queries cannot see stok keys
            } else {
                int dlt = gk - gq;
                dlt = dlt < -16 ? -16 : (dlt > 16 ? 16 : dlt);
                val += wsm[row * 33 + dlt + 16];
            }
        }
        uint8_t mk = (gk < STOK) ? mtok[(size_t)b * STOK + gk]
                                 : mstm[(size_t)b * STMN + gk - STOK];
        if (mk) val = NEGINF;
        sc[row * 644 + gk] = val;
    };

    for (int kt2 = 0; kt2 < 5; ++kt2) {
        const float* kg = kws + bh_off + (size_t)(kt2 * 128) * HD;
        __syncthreads();
#pragma unroll
        for (int j = 0; j < 8; ++j) {
            int f = t + j * 256;
            int row = f >> 4, c = f & 15;
            *reinterpret_cast<float4*>(&kvb[row * 68 + c * 4]) =
                *reinterpret_cast<const float4*>(&kg[(size_t)row * HD + c * 4]);
        }
        __syncthreads();
        float a00 = 0.f, a01 = 0.f, a10 = 0.f, a11 = 0.f;
#pragma unroll
        for (int dc = 0; dc < 16; ++dc) {
            float4 q0 = *reinterpret_cast<float4*>(&qsb[r0 * 64 + dc * 4]);
            float4 q1 = *reinterpret_cast<float4*>(&qsb[r1 * 64 + dc * 4]);
            float4 k0 = *reinterpret_cast<float4*>(&kvb[s_ * 68 + dc * 4]);
            float4 k1 = *reinterpret_cast<float4*>(&kvb[(s_ + 64) * 68 + dc * 4]);
            a00 += DOT4(q0, k0); a01 += DOT4(q0, k1);
            a10 += DOT4(q1, k0); a11 += DOT4(q1, k1);
        }
        int kb = kt2 * 128;
        handle(r0, kb + s_, a00);
        handle(r0, kb + 64 + s_, a01);
        handle(r1, kb + s_, a10);
        handle(r1, kb + 64 + s_, a11);
    }
    __syncthreads();

    // P2: softmax (row i owned by 32-lane group)
    {
        int i = t >> 5, s = t & 31;
        float m = -3.4e38f;
        for (int k = s; k < SS; k += 32) m = fmaxf(m, sc[i * 644 + k]);
#pragma unroll
        for (int off = 16; off; off >>= 1) m = fmaxf(m, __shfl_xor(m, off));
        float sum = 0.f;
        for (int k = s; k < SS; k += 32) {
            float e = __expf(sc[i * 644 + k] - m);
            sc[i * 644 + k] = e;
            sum += e;
        }
#pragma unroll
        for (int off = 16; off; off >>= 1) sum += __shfl_xor(sum, off);
        float inv = 1.0f / sum;
        for (int k = s; k < SS; k += 32) sc[i * 644 + k] *= inv;
    }
    __syncthreads();

    // attn output: 8*640 contiguous floats per block
    {
        float* dst = attn_out + ((size_t)bh * SS + qbase) * SS;
        for (int j = 0; j < 20; ++j) {
            int kf = t + j * 256;
            int row = kf / 640, k = kf - row * 640;
            dst[kf] = sc[row * 644 + k];
        }
    }

    // P3: PV main.  thread t: tp=t&127 -> (row3, f4-col c3); kh = key-half
    const int tp = t & 127;
    const int row3 = tp >> 4, c3 = tp & 15;
    const int kh = t >> 7;
    float4 acc = make_float4(0.f, 0.f, 0.f, 0.f);

    for (int kt2 = 0; kt2 < 5; ++kt2) {
        const float* vg = vws + bh_off + (size_t)(kt2 * 128) * HD;
        __syncthreads();
#pragma unroll
        for (int j = 0; j < 8; ++j) {
            int f = t + j * 256;
            int row = f >> 4, c = f & 15;
            *reinterpret_cast<float4*>(&kvb[row * 68 + c * 4]) =
                *reinterpret_cast<const float4*>(&vg[(size_t)row * HD + c * 4]);
        }
        __syncthreads();
        int kb = kh * 64;
#pragma unroll
        for (int k4 = 0; k4 < 16; ++k4) {
            float4 pv = *reinterpret_cast<float4*>(&sc[row3 * 644 + kt2 * 128 + kb + k4 * 4]);
            const float* vp = &kvb[(kb + k4 * 4) * 68 + c3 * 4];
            float4 v0 = *reinterpret_cast<const float4*>(vp);
            float4 v1 = *reinterpret_cast<const float4*>(vp + 68);
            float4 v2 = *reinterpret_cast<const float4*>(vp + 136);
            float4 v3 = *reinterpret_cast<const float4*>(vp + 204);
            acc.x += pv.x * v0.x + pv.y * v1.x + pv.z * v2.x + pv.w * v3.x;
            acc.y += pv.x * v0.y + pv.y * v1.y + pv.z * v2.y + pv.w * v3.y;
            acc.z += pv.x * v0.z + pv.y * v1.z + pv.z * v2.z + pv.w * v3.z;
            acc.w += pv.x * v0.w + pv.y * v1.w + pv.z * v2.w + pv.w * v3.w;
        }
    }
    __syncthreads();

    // P3.5: rel-v bins from probabilities; P4 load: relv tables into kvb
    {
        int i = t >> 5, s = t & 31;
        int gq = qbase + i;
        if (!q_stm) {
            for (int v = 1 + s; v < 64; v += 32) {
                int k = gq - 32 + v;
                wst[i * 65 + v] = (k >= 0 && k < STOK) ? sc[i * 644 + k] : 0.f;
            }
            float s0 = 0.f;
            for (int k = s; k <= gq - 32; k += 32) s0 += sc[i * 644 + k];
#pragma unroll
            for (int off = 16; off; off >>= 1) s0 += __shfl_xor(s0, off);
            float s1 = 0.f;
            for (int k = gq + 32 + s; k < STOK; k += 32) s1 += sc[i * 644 + k];
#pragma unroll
            for (int off = 16; off; off >>= 1) s1 += __shfl_xor(s1, off);
            if (s == 0) { wst[i * 65] = s0; wst[i * 65 + 64] = s1; }
        } else {
            int qp = gq - STOK;
            for (int v = 1 + s; v < 32; v += 32) {
                int kp = qp - 16 + v;
                wsm[i * 33 + v] = (kp >= 0 && kp < STMN) ? sc[i * 644 + STOK + kp] : 0.f;
            }
            float s0 = 0.f;
            for (int kp = s; kp <= qp - 16; kp += 32) s0 += sc[i * 644 + STOK + kp];
#pragma unroll
            for (int off = 16; off; off >>= 1) s0 += __shfl_xor(s0, off);
            float s1 = 0.f;
            for (int kp = qp + 16 + s; kp < STMN; kp += 32) s1 += sc[i * 644 + STOK + kp];
#pragma unroll
            for (int off = 16; off; off >>= 1) s1 += __shfl_xor(s1, off);
            if (s == 0) { wsm[i * 33] = s0; wsm[i * 33 + 32] = s1; }
        }
    }
    if (!q_stm) {
        for (int f = t; f < 65 * 16; f += 256)
            *reinterpret_cast<float4*>(&kvb[f * 4]) =
                *reinterpret_cast<const float4*>(&relv[(size_t)f * 4]);
    } else {
        for (int f = t; f < 33 * 16; f += 256)
            *reinterpret_cast<float4*>(&kvb[f * 4]) =
                *reinterpret_cast<const float4*>(&smv[(size_t)f * 4]);
    }
    __syncthreads();

    // P4b: rel-v contribution (v-range split across key-halves)
    {
        int vlo, vhi;
        if (!q_stm) { vlo = kh ? 33 : 0; vhi = kh ? 65 : 33; }
        else        { vlo = kh ? 17 : 0; vhi = kh ? 33 : 17; }
        for (int v = vlo; v < vhi; ++v) {
            float wv = q_stm ? wsm[row3 * 33 + v] : wst[row3 * 65 + v];
            float4 rv = *reinterpret_cast<float4*>(&kvb[v * 64 + c3 * 4]);
            acc.x += wv * rv.x; acc.y += wv * rv.y;
            acc.z += wv * rv.z; acc.w += wv * rv.w;
        }
    }

    // reduce key-halves through qsb scratch, write ctx [b][s][h*64+d]
    __syncthreads();
    if (kh == 1) *reinterpret_cast<float4*>(&qsb[tp * 4]) = acc;
    __syncthreads();
    if (kh == 0) {
        float4 o = *reinterpret_cast<float4*>(&qsb[tp * 4]);
        acc.x += o.x; acc.y += o.y; acc.z += o.z; acc.w += o.w;
        int gq = qbase + row3;
        float* cdst = ctx + ((size_t)b * SS + gq) * DIM + h * HD + c3 * 4;
        *reinterpret_cast<float4*>(cdst) = acc;
    }
}

// ---------------------------------------------------------------------------
extern "C" void kernel_launch(void* const* d_in, const int* in_sizes, int n_in,
                              void* d_out, int out_size, void* d_ws, size_t ws_size,
                              hipStream_t stream)
{
    const float*   stok  = (const float*)d_in[0];
    const float*   stm   = (const float*)d_in[1];
    const uint8_t* mtok  = (const uint8_t*)d_in[2];
    const uint8_t* mstm  = (const uint8_t*)d_in[3];
    const float*   qkv_w = (const float*)d_in[4];
    const float*   qkv_b = (const float*)d_in[5];
    const float*   out_w = (const float*)d_in[6];
    const float*   out_b = (const float*)d_in[7];
    const float*   relk  = (const float*)d_in[8];
    const float*   relv  = (const float*)d_in[9];
    const float*   smk   = (const float*)d_in[10];
    const float*   smv   = (const float*)d_in[11];

    float* out_final = (float*)d_out;
    float* out_attn  = out_final + (size_t)BB * SS * DIM;   // 5,242,880

    // workspace: q, k, v, ctx  (4 x 20.97 MB = 83.9 MB)
    float* ws = (float*)d_ws;
    const size_t SZ = (size_t)BB * HH * SS * HD;            // 5,242,880
    float* qws = ws;
    float* kws = ws + SZ;
    float* vws = ws + 2 * SZ;
    float* ctx = ws + 3 * SZ;

    gemm_qkv<<<dim3(960), dim3(256), 0, stream>>>(stok, stm, qkv_w, qkv_b, qws, kws, vws);
    attn_kernel<<<dim3(10240), dim3(256), 0, stream>>>(qws, kws, vws, mtok, mstm,
                                                       relk, relv, smk, smv, out_attn, ctx);
    gemm_out<<<dim3(320), dim3(256), 0, stream>>>(ctx, out_w, out_b, out_final);
}

// Round 2
// 1208.584 us; speedup vs baseline: 1.4876x; 1.4876x over previous
//
#include <hip/hip_runtime.h>
#include <stdint.h>

// Problem constants
#define BB    8
#define HH    16
#define SS    640
#define STOK  512
#define STMN  128
#define HD    64
#define DIM   1024
#define NEGINF (-1e18f)

typedef short v8s __attribute__((ext_vector_type(8)));
typedef float v4f __attribute__((ext_vector_type(4)));

static __device__ __forceinline__ ushort f2b(float f) {
    union { float f; uint32_t u; } x; x.f = f;
    uint32_t u = (x.u + 0x7FFFu + ((x.u >> 16) & 1u)) >> 16;
    return (ushort)u;
}
static __device__ __forceinline__ float b2f(ushort h) {
    union { uint32_t u; float f; } x; x.u = ((uint32_t)h) << 16;
    return x.f;
}

// ---------------------------------------------------------------------------
// Kernel A: QKV projection -> bf16 q[bh][s][d] (pre-scaled 1/8), k[bh][s][d],
// vT[bh][d][s].  128x128 tile, BK=8, 8x8 per thread, f32 accumulate.
// ---------------------------------------------------------------------------
__global__ __launch_bounds__(256) void gemm_qkv(
    const float* __restrict__ stok, const float* __restrict__ stm,
    const float* __restrict__ W, const float* __restrict__ bias,
    ushort* __restrict__ qb, ushort* __restrict__ kb, ushort* __restrict__ vtb)
{
    __shared__ float As[8][128];
    __shared__ float Bs[8][128];
    const int t  = threadIdx.x;
    const int mt = blockIdx.x / 24, nt = blockIdx.x % 24;
    const int mb = mt * 128, nb = nt * 128;
    const int b  = mb / SS, sb = mb % SS;
    const float* xbase = (sb >= STOK)
        ? (stm + ((size_t)b * STMN + (sb - STOK)) * DIM)
        : (stok + ((size_t)b * STOK + sb) * DIM);
    const int lr = t >> 1, lk = (t & 1) * 4;
    const float* ald = xbase + (size_t)lr * DIM + lk;
    const float* bld = W + (size_t)(nb + lr) * DIM + lk;
    const int ty = t >> 4, tx = t & 15;

    float acc[8][8];
#pragma unroll
    for (int i = 0; i < 8; ++i)
#pragma unroll
        for (int j = 0; j < 8; ++j) acc[i][j] = 0.f;

    for (int k0 = 0; k0 < DIM; k0 += 8) {
        float4 av = *reinterpret_cast<const float4*>(ald + k0);
        float4 bv = *reinterpret_cast<const float4*>(bld + k0);
        __syncthreads();
        As[lk + 0][lr] = av.x; As[lk + 1][lr] = av.y;
        As[lk + 2][lr] = av.z; As[lk + 3][lr] = av.w;
        Bs[lk + 0][lr] = bv.x; Bs[lk + 1][lr] = bv.y;
        Bs[lk + 2][lr] = bv.z; Bs[lk + 3][lr] = bv.w;
        __syncthreads();
#pragma unroll
        for (int kk = 0; kk < 8; ++kk) {
            float a[8], bbv[8];
            *reinterpret_cast<float4*>(a)     = *reinterpret_cast<float4*>(&As[kk][ty * 8]);
            *reinterpret_cast<float4*>(a + 4) = *reinterpret_cast<float4*>(&As[kk][ty * 8 + 4]);
            *reinterpret_cast<float4*>(bbv)     = *reinterpret_cast<float4*>(&Bs[kk][tx * 4]);
            *reinterpret_cast<float4*>(bbv + 4) = *reinterpret_cast<float4*>(&Bs[kk][64 + tx * 4]);
#pragma unroll
            for (int i = 0; i < 8; ++i)
#pragma unroll
                for (int j = 0; j < 8; ++j)
                    acc[i][j] = fmaf(a[i], bbv[j], acc[i][j]);
        }
    }

    const int nsel = nb >> 10;                 // 0=q 1=k 2=v (uniform per block)
    if (nsel < 2) {
        ushort* dst = (nsel == 0) ? qb : kb;
        const float scale = (nsel == 0) ? 0.125f : 1.0f;
#pragma unroll
        for (int g = 0; g < 2; ++g) {
            int nb2 = nb + g * 64;
            int h = (nb2 & 1023) >> 6;
            int dlo = tx * 4;
            float b0 = bias[nb2 + dlo], b1 = bias[nb2 + dlo + 1];
            float b2_ = bias[nb2 + dlo + 2], b3 = bias[nb2 + dlo + 3];
            size_t base = (((size_t)b * HH + h) * SS) * HD + dlo;
#pragma unroll
            for (int i = 0; i < 8; ++i) {
                int s = sb + ty * 8 + i;
                ushort4 pk;
                pk.x = f2b((acc[i][g * 4 + 0] + b0) * scale);
                pk.y = f2b((acc[i][g * 4 + 1] + b1) * scale);
                pk.z = f2b((acc[i][g * 4 + 2] + b2_) * scale);
                pk.w = f2b((acc[i][g * 4 + 3] + b3) * scale);
                *reinterpret_cast<ushort4*>(&dst[base + (size_t)s * HD]) = pk;
            }
        }
    } else {
#pragma unroll
        for (int g = 0; g < 2; ++g) {
            int nb2 = nb + g * 64;
            int h = (nb2 & 1023) >> 6;
#pragma unroll
            for (int jj = 0; jj < 4; ++jj) {
                int d = tx * 4 + jj;
                float bi = bias[nb2 + d];
                ushort pk[8];
#pragma unroll
                for (int i = 0; i < 8; ++i) pk[i] = f2b(acc[i][g * 4 + jj] + bi);
                size_t off = (((size_t)b * HH + h) * HD + d) * SS + (sb + ty * 8);
                uint4 wv;
                wv.x = (uint32_t)pk[0] | ((uint32_t)pk[1] << 16);
                wv.y = (uint32_t)pk[2] | ((uint32_t)pk[3] << 16);
                wv.z = (uint32_t)pk[4] | ((uint32_t)pk[5] << 16);
                wv.w = (uint32_t)pk[6] | ((uint32_t)pk[7] << 16);
                *reinterpret_cast<uint4*>(&vtb[off]) = wv;
            }
        }
    }
}

// ---------------------------------------------------------------------------
// Kernel C: out projection (f32, precision-critical).  ctx @ out_w.T + out_b
// ---------------------------------------------------------------------------
__global__ __launch_bounds__(256) void gemm_out(
    const float* __restrict__ X, const float* __restrict__ W,
    const float* __restrict__ bias, float* __restrict__ out)
{
    __shared__ float As[8][128];
    __shared__ float Bs[8][128];
    const int t  = threadIdx.x;
    const int mt = blockIdx.x / 8, nt = blockIdx.x % 8;
    const int mb = mt * 128, nb = nt * 128;
    const int lr = t >> 1, lk = (t & 1) * 4;
    const float* ald = X + (size_t)(mb + lr) * DIM + lk;
    const float* bld = W + (size_t)(nb + lr) * DIM + lk;
    const int ty = t >> 4, tx = t & 15;

    float acc[8][8];
#pragma unroll
    for (int i = 0; i < 8; ++i)
#pragma unroll
        for (int j = 0; j < 8; ++j) acc[i][j] = 0.f;

    for (int k0 = 0; k0 < DIM; k0 += 8) {
        float4 av = *reinterpret_cast<const float4*>(ald + k0);
        float4 bv = *reinterpret_cast<const float4*>(bld + k0);
        __syncthreads();
        As[lk + 0][lr] = av.x; As[lk + 1][lr] = av.y;
        As[lk + 2][lr] = av.z; As[lk + 3][lr] = av.w;
        Bs[lk + 0][lr] = bv.x; Bs[lk + 1][lr] = bv.y;
        Bs[lk + 2][lr] = bv.z; Bs[lk + 3][lr] = bv.w;
        __syncthreads();
#pragma unroll
        for (int kk = 0; kk < 8; ++kk) {
            float a[8], bbv[8];
            *reinterpret_cast<float4*>(a)     = *reinterpret_cast<float4*>(&As[kk][ty * 8]);
            *reinterpret_cast<float4*>(a + 4) = *reinterpret_cast<float4*>(&As[kk][ty * 8 + 4]);
            *reinterpret_cast<float4*>(bbv)     = *reinterpret_cast<float4*>(&Bs[kk][tx * 4]);
            *reinterpret_cast<float4*>(bbv + 4) = *reinterpret_cast<float4*>(&Bs[kk][64 + tx * 4]);
#pragma unroll
            for (int i = 0; i < 8; ++i)
#pragma unroll
                for (int j = 0; j < 8; ++j)
                    acc[i][j] = fmaf(a[i], bbv[j], acc[i][j]);
        }
    }
#pragma unroll
    for (int j = 0; j < 8; ++j) {
        int n = nb + (j < 4 ? tx * 4 + j : 64 + tx * 4 + (j - 4));
        float bia = bias[n];
#pragma unroll
        for (int i = 0; i < 8; ++i) {
            int m = mb + ty * 8 + i;
            out[(size_t)m * DIM + n] = acc[i][j] + bia;
        }
    }
}

// ---------------------------------------------------------------------------
// Kernel B: MFMA attention.  Block = (b,h) x 64 q-rows; 4 waves x 16 rows.
// Sweep1: exp-sums (no max; scores are O(3)).  Sweep2: recompute scores,
// write probs, stage P bf16, bin rel-v weights, PV MFMA.  Rel-v = one extra
// virtual PV tile (A=wbin, B=relv^T) + rank-1 fixup for bin 64.
// ---------------------------------------------------------------------------
__global__ __launch_bounds__(256) void attn_mfma(
    const ushort* __restrict__ qb, const ushort* __restrict__ kb,
    const ushort* __restrict__ vtb,
    const uint8_t* __restrict__ mtok, const uint8_t* __restrict__ mstm,
    const float* __restrict__ relk, const float* __restrict__ relv,
    const float* __restrict__ smk,  const float* __restrict__ smv,
    float* __restrict__ attn_out, float* __restrict__ ctx)
{
    __shared__ ushort Qlds[64][72];
    __shared__ ushort Klds[64][72];
    __shared__ ushort VTlds[64][72];
    __shared__ ushort Plds[64][72];
    __shared__ ushort qrel[64][72];
    __shared__ float  wbin[64][65];

    const int t    = threadIdx.x;
    const int lane = t & 63, w = t >> 6;
    const int qt = blockIdx.x % 10, bh = blockIdx.x / 10;
    const int b = bh >> 4, h = bh & 15;
    const int qbase = qt * 64;
    const bool qstm = (qt >= 8);
    const size_t bhoff = (size_t)bh * (SS * HD);

    // zero wbin
    for (int i = t; i < 64 * 65; i += 256) (&wbin[0][0])[i] = 0.f;

    // stage Q (64 rows x 8 slots of 8 bf16)
    for (int c = t; c < 512; c += 256) {
        int r = c >> 3, sl = c & 7;
        *reinterpret_cast<uint4*>(&Qlds[r][sl * 8]) =
            *reinterpret_cast<const uint4*>(&qb[bhoff + (size_t)(qbase + r) * HD + sl * 8]);
    }

    // stm blocks: zero attn cols 0..511 (scores are -inf there)
    if (qstm) {
        float4 z = make_float4(0.f, 0.f, 0.f, 0.f);
        float* dst = attn_out + ((size_t)bh * SS + qbase) * SS;
        for (int idx = t; idx < 64 * 128; idx += 256) {
            int r = idx >> 7, c4 = idx & 127;
            *reinterpret_cast<float4*>(&dst[(size_t)r * SS + c4 * 4]) = z;
        }
    }
    __syncthreads();

    // qrel[i][v] = q_i . rel_emb_k[v]  (bf16 table)
    const int  NV   = qstm ? 33 : 65;
    const int  RR   = qstm ? 16 : 32;
    const float* tabk = qstm ? smk : relk;
    {
        int i = t >> 2;
        for (int v = (t & 3); v < NV; v += 4) {
            float a = 0.f;
#pragma unroll
            for (int dc = 0; dc < 8; ++dc) {
                uint4 qq = *reinterpret_cast<uint4*>(&Qlds[i][dc * 8]);
                float4 t0 = *reinterpret_cast<const float4*>(&tabk[v * HD + dc * 8]);
                float4 t1 = *reinterpret_cast<const float4*>(&tabk[v * HD + dc * 8 + 4]);
                a += b2f((ushort)(qq.x & 0xffff)) * t0.x + b2f((ushort)(qq.x >> 16)) * t0.y
                   + b2f((ushort)(qq.y & 0xffff)) * t0.z + b2f((ushort)(qq.y >> 16)) * t0.w
                   + b2f((ushort)(qq.z & 0xffff)) * t1.x + b2f((ushort)(qq.z >> 16)) * t1.y
                   + b2f((ushort)(qq.w & 0xffff)) * t1.z + b2f((ushort)(qq.w >> 16)) * t1.w;
            }
            qrel[i][v] = f2b(a);
        }
    }
    __syncthreads();

    const int wq = w * 16;            // wave's q-row base (local)
    const int lg = lane >> 4;         // lane group
    const int lc = lane & 15;         // col within tile / A-frag row
    // hoisted Q A-fragments (constant across all k-tiles)
    v8s aq0 = *reinterpret_cast<const v8s*>(&Qlds[wq + lc][lg * 8]);
    v8s aq1 = *reinterpret_cast<const v8s*>(&Qlds[wq + lc][32 + lg * 8]);

    const int tile0 = qstm ? 8 : 0;
    float lsum[4] = {0.f, 0.f, 0.f, 0.f};

    // ---- sweep 1: exp-sums ----
    for (int kt = tile0; kt < 10; ++kt) {
        __syncthreads();
        for (int c = t; c < 512; c += 256) {
            int r = c >> 3, sl = c & 7;
            *reinterpret_cast<uint4*>(&Klds[r][sl * 8]) =
                *reinterpret_cast<const uint4*>(&kb[bhoff + (size_t)(kt * 64 + r) * HD + sl * 8]);
        }
        __syncthreads();
        const bool dorel = qstm || (kt < 8);
#pragma unroll
        for (int sub = 0; sub < 4; ++sub) {
            v8s bk0 = *reinterpret_cast<const v8s*>(&Klds[sub * 16 + lc][lg * 8]);
            v8s bk1 = *reinterpret_cast<const v8s*>(&Klds[sub * 16 + lc][32 + lg * 8]);
            v4f c4 = {0.f, 0.f, 0.f, 0.f};
            c4 = __builtin_amdgcn_mfma_f32_16x16x32_bf16(aq0, bk0, c4, 0, 0, 0);
            c4 = __builtin_amdgcn_mfma_f32_16x16x32_bf16(aq1, bk1, c4, 0, 0, 0);
            int kg = kt * 64 + sub * 16 + lc;
            uint8_t mk = (kg < STOK) ? mtok[b * STOK + kg] : mstm[b * STMN + kg - STOK];
#pragma unroll
            for (int r = 0; r < 4; ++r) {
                int lq = wq + lg * 4 + r;
                float val = c4[r];
                if (dorel) {
                    int dlt = kg - (qbase + lq);
                    dlt = dlt < -RR ? -RR : (dlt > RR ? RR : dlt);
                    val += b2f(qrel[lq][dlt + RR]);
                }
                if (mk) val = NEGINF;
                lsum[r] += __expf(val);
            }
        }
    }

    // reduce over the 16 column-lanes
    float invl[4];
#pragma unroll
    for (int r = 0; r < 4; ++r) {
        float s = lsum[r];
        s += __shfl_xor(s, 1); s += __shfl_xor(s, 2);
        s += __shfl_xor(s, 4); s += __shfl_xor(s, 8);
        invl[r] = 1.f / s;
    }

    v4f o[4];
#pragma unroll
    for (int dt = 0; dt < 4; ++dt) o[dt] = (v4f){0.f, 0.f, 0.f, 0.f};
    float* arow = attn_out + ((size_t)bh * SS + qbase) * SS;

    // ---- sweep 2: probs + PV ----
    for (int kt = tile0; kt < 10; ++kt) {
        __syncthreads();
        for (int c = t; c < 1024; c += 256) {
            int buf = c >> 9, cc = c & 511;
            int r = cc >> 3, sl = cc & 7;
            if (buf == 0)
                *reinterpret_cast<uint4*>(&Klds[r][sl * 8]) =
                    *reinterpret_cast<const uint4*>(&kb[bhoff + (size_t)(kt * 64 + r) * HD + sl * 8]);
            else
                *reinterpret_cast<uint4*>(&VTlds[r][sl * 8]) =
                    *reinterpret_cast<const uint4*>(&vtb[bhoff + (size_t)r * SS + kt * 64 + sl * 8]);
        }
        __syncthreads();
        const bool dorel = qstm || (kt < 8);
#pragma unroll
        for (int sub = 0; sub < 4; ++sub) {
            v8s bk0 = *reinterpret_cast<const v8s*>(&Klds[sub * 16 + lc][lg * 8]);
            v8s bk1 = *reinterpret_cast<const v8s*>(&Klds[sub * 16 + lc][32 + lg * 8]);
            v4f c4 = {0.f, 0.f, 0.f, 0.f};
            c4 = __builtin_amdgcn_mfma_f32_16x16x32_bf16(aq0, bk0, c4, 0, 0, 0);
            c4 = __builtin_amdgcn_mfma_f32_16x16x32_bf16(aq1, bk1, c4, 0, 0, 0);
            int kg = kt * 64 + sub * 16 + lc;
            uint8_t mk = (kg < STOK) ? mtok[b * STOK + kg] : mstm[b * STMN + kg - STOK];
#pragma unroll
            for (int r = 0; r < 4; ++r) {
                int lq = wq + lg * 4 + r;
                float val = c4[r];
                int dlt = kg - (qbase + lq);
                dlt = dlt < -RR ? -RR : (dlt > RR ? RR : dlt);
                if (dorel) val += b2f(qrel[lq][dlt + RR]);
                if (mk) val = NEGINF;
                float p = __expf(val) * invl[r];
                arow[(size_t)lq * SS + kg] = p;
                Plds[lq][sub * 16 + lc] = f2b(p);
                if (dorel) atomicAdd(&wbin[lq][dlt + RR], p);
            }
        }
        // PV for this tile (Plds rows are wave-private; LDS per-wave in-order)
        v8s ap0 = *reinterpret_cast<const v8s*>(&Plds[wq + lc][lg * 8]);
        v8s ap1 = *reinterpret_cast<const v8s*>(&Plds[wq + lc][32 + lg * 8]);
#pragma unroll
        for (int dt = 0; dt < 4; ++dt) {
            v8s bv0 = *reinterpret_cast<const v8s*>(&VTlds[dt * 16 + lc][lg * 8]);
            v8s bv1 = *reinterpret_cast<const v8s*>(&VTlds[dt * 16 + lc][32 + lg * 8]);
            o[dt] = __builtin_amdgcn_mfma_f32_16x16x32_bf16(ap0, bv0, o[dt], 0, 0, 0);
            o[dt] = __builtin_amdgcn_mfma_f32_16x16x32_bf16(ap1, bv1, o[dt], 0, 0, 0);
        }
    }

    // ---- rel-v virtual tile ----
    __syncthreads();
    {
        const float* tabv = qstm ? smv : relv;
        const int NV2 = qstm ? 33 : 65;
        for (int idx = t; idx < 64 * 64; idx += 256) {
            int v = idx >> 6, d = idx & 63;
            float f = (v < NV2 && v < 64) ? tabv[v * HD + d] : 0.f;
            VTlds[d][v] = f2b(f);
        }
        for (int idx = t; idx < 64 * 64; idx += 256) {
            int rr = idx >> 6, v = idx & 63;
            float f = (v < NV2) ? wbin[rr][v] : 0.f;
            Plds[rr][v] = f2b(f);
        }
    }
    __syncthreads();
    {
        v8s ap0 = *reinterpret_cast<const v8s*>(&Plds[wq + lc][lg * 8]);
        v8s ap1 = *reinterpret_cast<const v8s*>(&Plds[wq + lc][32 + lg * 8]);
#pragma unroll
        for (int dt = 0; dt < 4; ++dt) {
            v8s bv0 = *reinterpret_cast<const v8s*>(&VTlds[dt * 16 + lc][lg * 8]);
            v8s bv1 = *reinterpret_cast<const v8s*>(&VTlds[dt * 16 + lc][32 + lg * 8]);
            o[dt] = __builtin_amdgcn_mfma_f32_16x16x32_bf16(ap0, bv0, o[dt], 0, 0, 0);
            o[dt] = __builtin_amdgcn_mfma_f32_16x16x32_bf16(ap1, bv1, o[dt], 0, 0, 0);
        }
        if (!qstm) {   // rank-1 fixup for bin v=64
#pragma unroll
            for (int r = 0; r < 4; ++r) {
                float wv = wbin[wq + lg * 4 + r][64];
#pragma unroll
                for (int dt = 0; dt < 4; ++dt)
                    o[dt][r] += wv * relv[64 * HD + dt * 16 + lc];
            }
        }
    }

    // write ctx f32 [b][s][h*64+d]
#pragma unroll
    for (int dt = 0; dt < 4; ++dt)
#pragma unroll
        for (int r = 0; r < 4; ++r) {
            int gq = qbase + wq + lg * 4 + r;
            ctx[((size_t)b * SS + gq) * DIM + h * HD + dt * 16 + lc] = o[dt][r];
        }
}

// ---------------------------------------------------------------------------
extern "C" void kernel_launch(void* const* d_in, const int* in_sizes, int n_in,
                              void* d_out, int out_size, void* d_ws, size_t ws_size,
                              hipStream_t stream)
{
    const float*   stok  = (const float*)d_in[0];
    const float*   stm   = (const float*)d_in[1];
    const uint8_t* mtok  = (const uint8_t*)d_in[2];
    const uint8_t* mstm  = (const uint8_t*)d_in[3];
    const float*   qkv_w = (const float*)d_in[4];
    const float*   qkv_b = (const float*)d_in[5];
    const float*   out_w = (const float*)d_in[6];
    const float*   out_b = (const float*)d_in[7];
    const float*   relk  = (const float*)d_in[8];
    const float*   relv  = (const float*)d_in[9];
    const float*   smk   = (const float*)d_in[10];
    const float*   smv   = (const float*)d_in[11];

    float* out_final = (float*)d_out;
    float* out_attn  = out_final + (size_t)BB * SS * DIM;

    const size_t SZ = (size_t)BB * HH * SS * HD;           // 5,242,880
    ushort* qb16 = (ushort*)d_ws;
    ushort* kb16 = qb16 + SZ;
    ushort* vt16 = kb16 + SZ;
    float*  ctx  = (float*)(vt16 + SZ);                    // 31.4 MB offset, 4B aligned

    gemm_qkv<<<dim3(960), dim3(256), 0, stream>>>(stok, stm, qkv_w, qkv_b, qb16, kb16, vt16);
    attn_mfma<<<dim3(1280), dim3(256), 0, stream>>>(qb16, kb16, vt16, mtok, mstm,
                                                    relk, relv, smk, smv, out_attn, ctx);
    gemm_out<<<dim3(320), dim3(256), 0, stream>>>(ctx, out_w, out_b, out_final);
}

// Round 3
// 748.392 us; speedup vs baseline: 2.4023x; 1.6149x over previous
//
#include <hip/hip_runtime.h>
#include <stdint.h>

// Problem constants
#define BB    8
#define HH    16
#define SS    640
#define STOK  512
#define STMN  128
#define HD    64
#define DIM   1024
#define NEGINF (-1e18f)

typedef short v8s __attribute__((ext_vector_type(8)));
typedef float v4f __attribute__((ext_vector_type(4)));

static __device__ __forceinline__ ushort f2b(float f) {
    union { float f; uint32_t u; } x; x.f = f;
    uint32_t u = (x.u + 0x7FFFu + ((x.u >> 16) & 1u)) >> 16;
    return (ushort)u;
}
static __device__ __forceinline__ float b2f(ushort h) {
    union { uint32_t u; float f; } x; x.u = ((uint32_t)h) << 16;
    return x.f;
}

// ---------------------------------------------------------------------------
// Kernel A: QKV projection -> bf16 q[bh][s][d] (pre-scaled 1/8), k[bh][s][d],
// vT[bh][d][s].  128x128 tile, BK=8, 8x8 per thread, f32 accumulate.
// ---------------------------------------------------------------------------
__global__ __launch_bounds__(256) void gemm_qkv(
    const float* __restrict__ stok, const float* __restrict__ stm,
    const float* __restrict__ W, const float* __restrict__ bias,
    ushort* __restrict__ qb, ushort* __restrict__ kb, ushort* __restrict__ vtb)
{
    __shared__ float As[8][128];
    __shared__ float Bs[8][128];
    const int t  = threadIdx.x;
    const int mt = blockIdx.x / 24, nt = blockIdx.x % 24;
    const int mb = mt * 128, nb = nt * 128;
    const int b  = mb / SS, sb = mb % SS;
    const float* xbase = (sb >= STOK)
        ? (stm + ((size_t)b * STMN + (sb - STOK)) * DIM)
        : (stok + ((size_t)b * STOK + sb) * DIM);
    const int lr = t >> 1, lk = (t & 1) * 4;
    const float* ald = xbase + (size_t)lr * DIM + lk;
    const float* bld = W + (size_t)(nb + lr) * DIM + lk;
    const int ty = t >> 4, tx = t & 15;

    float acc[8][8];
#pragma unroll
    for (int i = 0; i < 8; ++i)
#pragma unroll
        for (int j = 0; j < 8; ++j) acc[i][j] = 0.f;

    for (int k0 = 0; k0 < DIM; k0 += 8) {
        float4 av = *reinterpret_cast<const float4*>(ald + k0);
        float4 bv = *reinterpret_cast<const float4*>(bld + k0);
        __syncthreads();
        As[lk + 0][lr] = av.x; As[lk + 1][lr] = av.y;
        As[lk + 2][lr] = av.z; As[lk + 3][lr] = av.w;
        Bs[lk + 0][lr] = bv.x; Bs[lk + 1][lr] = bv.y;
        Bs[lk + 2][lr] = bv.z; Bs[lk + 3][lr] = bv.w;
        __syncthreads();
#pragma unroll
        for (int kk = 0; kk < 8; ++kk) {
            float a[8], bbv[8];
            *reinterpret_cast<float4*>(a)     = *reinterpret_cast<float4*>(&As[kk][ty * 8]);
            *reinterpret_cast<float4*>(a + 4) = *reinterpret_cast<float4*>(&As[kk][ty * 8 + 4]);
            *reinterpret_cast<float4*>(bbv)     = *reinterpret_cast<float4*>(&Bs[kk][tx * 4]);
            *reinterpret_cast<float4*>(bbv + 4) = *reinterpret_cast<float4*>(&Bs[kk][64 + tx * 4]);
#pragma unroll
            for (int i = 0; i < 8; ++i)
#pragma unroll
                for (int j = 0; j < 8; ++j)
                    acc[i][j] = fmaf(a[i], bbv[j], acc[i][j]);
        }
    }

    const int nsel = nb >> 10;                 // 0=q 1=k 2=v (uniform per block)
    if (nsel < 2) {
        ushort* dst = (nsel == 0) ? qb : kb;
        const float scale = (nsel == 0) ? 0.125f : 1.0f;
#pragma unroll
        for (int g = 0; g < 2; ++g) {
            int nb2 = nb + g * 64;
            int h = (nb2 & 1023) >> 6;
            int dlo = tx * 4;
            float b0 = bias[nb2 + dlo], b1 = bias[nb2 + dlo + 1];
            float b2_ = bias[nb2 + dlo + 2], b3 = bias[nb2 + dlo + 3];
            size_t base = (((size_t)b * HH + h) * SS) * HD + dlo;
#pragma unroll
            for (int i = 0; i < 8; ++i) {
                int s = sb + ty * 8 + i;
                ushort4 pk;
                pk.x = f2b((acc[i][g * 4 + 0] + b0) * scale);
                pk.y = f2b((acc[i][g * 4 + 1] + b1) * scale);
                pk.z = f2b((acc[i][g * 4 + 2] + b2_) * scale);
                pk.w = f2b((acc[i][g * 4 + 3] + b3) * scale);
                *reinterpret_cast<ushort4*>(&dst[base + (size_t)s * HD]) = pk;
            }
        }
    } else {
#pragma unroll
        for (int g = 0; g < 2; ++g) {
            int nb2 = nb + g * 64;
            int h = (nb2 & 1023) >> 6;
#pragma unroll
            for (int jj = 0; jj < 4; ++jj) {
                int d = tx * 4 + jj;
                float bi = bias[nb2 + d];
                ushort pk[8];
#pragma unroll
                for (int i = 0; i < 8; ++i) pk[i] = f2b(acc[i][g * 4 + jj] + bi);
                size_t off = (((size_t)b * HH + h) * HD + d) * SS + (sb + ty * 8);
                uint4 wv;
                wv.x = (uint32_t)pk[0] | ((uint32_t)pk[1] << 16);
                wv.y = (uint32_t)pk[2] | ((uint32_t)pk[3] << 16);
                wv.z = (uint32_t)pk[4] | ((uint32_t)pk[5] << 16);
                wv.w = (uint32_t)pk[6] | ((uint32_t)pk[7] << 16);
                *reinterpret_cast<uint4*>(&vtb[off]) = wv;
            }
        }
    }
}

// ---------------------------------------------------------------------------
// Kernel C: out projection (f32, precision-critical).  ctx @ out_w.T + out_b
// ---------------------------------------------------------------------------
__global__ __launch_bounds__(256) void gemm_out(
    const float* __restrict__ X, const float* __restrict__ W,
    const float* __restrict__ bias, float* __restrict__ out)
{
    __shared__ float As[8][128];
    __shared__ float Bs[8][128];
    const int t  = threadIdx.x;
    const int mt = blockIdx.x / 8, nt = blockIdx.x % 8;
    const int mb = mt * 128, nb = nt * 128;
    const int lr = t >> 1, lk = (t & 1) * 4;
    const float* ald = X + (size_t)(mb + lr) * DIM + lk;
    const float* bld = W + (size_t)(nb + lr) * DIM + lk;
    const int ty = t >> 4, tx = t & 15;

    float acc[8][8];
#pragma unroll
    for (int i = 0; i < 8; ++i)
#pragma unroll
        for (int j = 0; j < 8; ++j) acc[i][j] = 0.f;

    for (int k0 = 0; k0 < DIM; k0 += 8) {
        float4 av = *reinterpret_cast<const float4*>(ald + k0);
        float4 bv = *reinterpret_cast<const float4*>(bld + k0);
        __syncthreads();
        As[lk + 0][lr] = av.x; As[lk + 1][lr] = av.y;
        As[lk + 2][lr] = av.z; As[lk + 3][lr] = av.w;
        Bs[lk + 0][lr] = bv.x; Bs[lk + 1][lr] = bv.y;
        Bs[lk + 2][lr] = bv.z; Bs[lk + 3][lr] = bv.w;
        __syncthreads();
#pragma unroll
        for (int kk = 0; kk < 8; ++kk) {
            float a[8], bbv[8];
            *reinterpret_cast<float4*>(a)     = *reinterpret_cast<float4*>(&As[kk][ty * 8]);
            *reinterpret_cast<float4*>(a + 4) = *reinterpret_cast<float4*>(&As[kk][ty * 8 + 4]);
            *reinterpret_cast<float4*>(bbv)     = *reinterpret_cast<float4*>(&Bs[kk][tx * 4]);
            *reinterpret_cast<float4*>(bbv + 4) = *reinterpret_cast<float4*>(&Bs[kk][64 + tx * 4]);
#pragma unroll
            for (int i = 0; i < 8; ++i)
#pragma unroll
                for (int j = 0; j < 8; ++j)
                    acc[i][j] = fmaf(a[i], bbv[j], acc[i][j]);
        }
    }
#pragma unroll
    for (int j = 0; j < 8; ++j) {
        int n = nb + (j < 4 ? tx * 4 + j : 64 + tx * 4 + (j - 4));
        float bia = bias[n];
#pragma unroll
        for (int i = 0; i < 8; ++i) {
            int m = mb + ty * 8 + i;
            out[(size_t)m * DIM + n] = acc[i][j] + bia;
        }
    }
}

// ---------------------------------------------------------------------------
// Kernel B: barrier-free MFMA attention.  Block = (b,h) x 64 q-rows; 4 waves
// x 16 rows, fully wave-independent (LDS row-partitioned).  K/V/Q fragments
// read directly from global (L1/L2-served).  Two sweeps: (1) exp-sums,
// (2) probs + attn write + PV + bin.  Rel-v = one extra MFMA tile.
// ---------------------------------------------------------------------------
__global__ __launch_bounds__(256, 4) void attn_mfma(
    const ushort* __restrict__ qb, const ushort* __restrict__ kb,
    const ushort* __restrict__ vtb,
    const uint8_t* __restrict__ mtok, const uint8_t* __restrict__ mstm,
    const float* __restrict__ relk, const float* __restrict__ relv,
    const float* __restrict__ smk,  const float* __restrict__ smv,
    float* __restrict__ attn_out, float* __restrict__ ctx)
{
    __shared__ ushort qrel[64][72];
    __shared__ ushort Plds[64][72];
    __shared__ ushort wbin[64][72];

    const int t    = threadIdx.x;
    const int lane = t & 63, w = t >> 6;
    const int swz  = ((blockIdx.x & 7) * 160) + (blockIdx.x >> 3);  // XCD-contiguous
    const int qt = swz % 10, bh = swz / 10;
    const int b = bh >> 4, h = bh & 15;
    const int qbase = qt * 64;
    const bool qstm = (qt >= 8);
    const size_t bhoff = (size_t)bh * (SS * HD);
    const int wq = w * 16, lg = lane >> 4, lc = lane & 15;
    const int RR = qstm ? 16 : 32;
    const int NV = qstm ? 33 : 65;
    const float* tabk = qstm ? smk : relk;

    // zero this wave's wbin rows (own rows only -> no barrier needed)
    for (int i = lane; i < 16 * 36; i += 64) {
        int r = i / 36, c = i - r * 36;
        *reinterpret_cast<uint32_t*>(&wbin[wq + r][c * 2]) = 0u;
    }

    // stm blocks: zero attn cols 0..511 (scores are -inf there)
    if (qstm) {
        float4 z = make_float4(0.f, 0.f, 0.f, 0.f);
        float* dst = attn_out + ((size_t)bh * SS + qbase) * SS;
        for (int idx = t; idx < 64 * 128; idx += 256) {
            int r = idx >> 7, c4 = idx & 127;
            *reinterpret_cast<float4*>(&dst[(size_t)r * SS + c4 * 4]) = z;
        }
    }

    // Q A-fragments straight from global (row = qbase+wq+lc)
    const int qrow = qbase + wq + lc;
    v8s aq0 = *reinterpret_cast<const v8s*>(&qb[bhoff + (size_t)qrow * HD + lg * 8]);
    v8s aq1 = *reinterpret_cast<const v8s*>(&qb[bhoff + (size_t)qrow * HD + 32 + lg * 8]);

    // qrel[i][v] = q_i . rel_emb_k[v] via MFMA (wave's own 16 rows)
    {
        const int ndt = qstm ? 2 : 4;
        for (int dt = 0; dt < ndt; ++dt) {
            const float* rp = tabk + (size_t)(dt * 16 + lc) * HD;
            v8s bk0, bk1;
#pragma unroll
            for (int j = 0; j < 8; ++j) {
                bk0[j] = (short)f2b(rp[lg * 8 + j]);
                bk1[j] = (short)f2b(rp[32 + lg * 8 + j]);
            }
            v4f c4 = {0.f, 0.f, 0.f, 0.f};
            c4 = __builtin_amdgcn_mfma_f32_16x16x32_bf16(aq0, bk0, c4, 0, 0, 0);
            c4 = __builtin_amdgcn_mfma_f32_16x16x32_bf16(aq1, bk1, c4, 0, 0, 0);
#pragma unroll
            for (int r = 0; r < 4; ++r)
                qrel[wq + lg * 4 + r][dt * 16 + lc] = f2b(c4[r]);
        }
        // last column v = NV-1 (row NV-1 of table), scalar partial + shfl
        const float* rp = tabk + (size_t)(NV - 1) * HD;
        float part = 0.f;
#pragma unroll
        for (int j = 0; j < 8; ++j) {
            part += b2f((ushort)aq0[j]) * rp[lg * 8 + j];
            part += b2f((ushort)aq1[j]) * rp[32 + lg * 8 + j];
        }
        part += __shfl_xor(part, 16);
        part += __shfl_xor(part, 32);
        if (lg == 0) qrel[wq + lc][NV - 1] = f2b(part);
    }

    const int tile0 = qstm ? 8 : 0;
    float lsum[4] = {0.f, 0.f, 0.f, 0.f};

    // ---- sweep 1: exp-sums (K-frags from global, no barriers) ----
    for (int kt = tile0; kt < 10; ++kt) {
        const ushort* kbase = kb + bhoff + (size_t)(kt * 64) * HD;
        const bool dorel = qstm || (kt < 8);
#pragma unroll
        for (int sub = 0; sub < 4; ++sub) {
            v8s bk0 = *reinterpret_cast<const v8s*>(&kbase[(sub * 16 + lc) * HD + lg * 8]);
            v8s bk1 = *reinterpret_cast<const v8s*>(&kbase[(sub * 16 + lc) * HD + 32 + lg * 8]);
            v4f c4 = {0.f, 0.f, 0.f, 0.f};
            c4 = __builtin_amdgcn_mfma_f32_16x16x32_bf16(aq0, bk0, c4, 0, 0, 0);
            c4 = __builtin_amdgcn_mfma_f32_16x16x32_bf16(aq1, bk1, c4, 0, 0, 0);
            int kg = kt * 64 + sub * 16 + lc;
            uint8_t mk = (kg < STOK) ? mtok[b * STOK + kg] : mstm[b * STMN + kg - STOK];
#pragma unroll
            for (int r = 0; r < 4; ++r) {
                int lq = wq + lg * 4 + r;
                float val = c4[r];
                if (dorel) {
                    int dlt = kg - (qbase + lq);
                    dlt = dlt < -RR ? -RR : (dlt > RR ? RR : dlt);
                    val += b2f(qrel[lq][dlt + RR]);
                }
                if (mk) val = NEGINF;
                lsum[r] += __expf(val);
            }
        }
    }

    float invl[4];
#pragma unroll
    for (int r = 0; r < 4; ++r) {
        float s = lsum[r];
        s += __shfl_xor(s, 1); s += __shfl_xor(s, 2);
        s += __shfl_xor(s, 4); s += __shfl_xor(s, 8);
        invl[r] = 1.f / s;
    }

    v4f o[4];
#pragma unroll
    for (int dt = 0; dt < 4; ++dt) o[dt] = (v4f){0.f, 0.f, 0.f, 0.f};
    float e0l[4] = {0.f, 0.f, 0.f, 0.f};
    float e1l[4] = {0.f, 0.f, 0.f, 0.f};
    float* arow = attn_out + ((size_t)bh * SS + qbase) * SS;

    // ---- sweep 2: probs + attn write + bins + PV (no barriers) ----
    for (int kt = tile0; kt < 10; ++kt) {
        const ushort* kbase = kb + bhoff + (size_t)(kt * 64) * HD;
        const bool dorel = qstm || (kt < 8);
#pragma unroll
        for (int sub = 0; sub < 4; ++sub) {
            v8s bk0 = *reinterpret_cast<const v8s*>(&kbase[(sub * 16 + lc) * HD + lg * 8]);
            v8s bk1 = *reinterpret_cast<const v8s*>(&kbase[(sub * 16 + lc) * HD + 32 + lg * 8]);
            v4f c4 = {0.f, 0.f, 0.f, 0.f};
            c4 = __builtin_amdgcn_mfma_f32_16x16x32_bf16(aq0, bk0, c4, 0, 0, 0);
            c4 = __builtin_amdgcn_mfma_f32_16x16x32_bf16(aq1, bk1, c4, 0, 0, 0);
            int kg = kt * 64 + sub * 16 + lc;
            uint8_t mk = (kg < STOK) ? mtok[b * STOK + kg] : mstm[b * STMN + kg - STOK];
#pragma unroll
            for (int r = 0; r < 4; ++r) {
                int lq = wq + lg * 4 + r;
                int dlt = kg - (qbase + lq);
                int dc = dlt < -RR ? -RR : (dlt > RR ? RR : dlt);
                float val = c4[r];
                if (dorel) val += b2f(qrel[lq][dc + RR]);
                if (mk) val = NEGINF;
                float p = __expf(val) * invl[r];
                arow[(size_t)lq * SS + kg] = p;
                Plds[lq][sub * 16 + lc] = f2b(p);
                if (dorel) {
                    if (dlt > -RR && dlt < RR) wbin[lq][dlt + RR] = f2b(p);
                    else if (dlt <= -RR) e0l[r] += p;
                    else e1l[r] += p;
                }
            }
        }
        // PV for this tile (A from own Plds rows, B = V^T frags from global)
        v8s ap0 = *reinterpret_cast<const v8s*>(&Plds[wq + lc][lg * 8]);
        v8s ap1 = *reinterpret_cast<const v8s*>(&Plds[wq + lc][32 + lg * 8]);
        const ushort* vbase = vtb + bhoff + kt * 64;
#pragma unroll
        for (int dt = 0; dt < 4; ++dt) {
            v8s bv0 = *reinterpret_cast<const v8s*>(&vbase[(size_t)(dt * 16 + lc) * SS + lg * 8]);
            v8s bv1 = *reinterpret_cast<const v8s*>(&vbase[(size_t)(dt * 16 + lc) * SS + 32 + lg * 8]);
            o[dt] = __builtin_amdgcn_mfma_f32_16x16x32_bf16(ap0, bv0, o[dt], 0, 0, 0);
            o[dt] = __builtin_amdgcn_mfma_f32_16x16x32_bf16(ap1, bv1, o[dt], 0, 0, 0);
        }
    }

    // edge-bin reduce (over the 16 col-lanes) + write; e1 kept for stok fixup
    float e1s[4];
#pragma unroll
    for (int r = 0; r < 4; ++r) {
        float s0 = e0l[r], s1 = e1l[r];
        s0 += __shfl_xor(s0, 1); s0 += __shfl_xor(s0, 2);
        s0 += __shfl_xor(s0, 4); s0 += __shfl_xor(s0, 8);
        s1 += __shfl_xor(s1, 1); s1 += __shfl_xor(s1, 2);
        s1 += __shfl_xor(s1, 4); s1 += __shfl_xor(s1, 8);
        e1s[r] = s1;
        if (lc == 0) {
            wbin[wq + lg * 4 + r][0] = f2b(s0);
            if (qstm) wbin[wq + lg * 4 + r][32] = f2b(s1);
        }
    }

    // ---- rel-v virtual tile: stage relv^T into Plds (cross-wave) ----
    __syncthreads();
    {
        const float* tabv = qstm ? smv : relv;
        for (int idx = t; idx < 64 * 64; idx += 256) {
            int d = idx >> 6, v = idx & 63;
            float f = (v < NV) ? tabv[(size_t)v * HD + d] : 0.f;
            Plds[d][v] = f2b(f);
        }
    }
    __syncthreads();
    {
        v8s aw0 = *reinterpret_cast<const v8s*>(&wbin[wq + lc][lg * 8]);
        v8s aw1 = *reinterpret_cast<const v8s*>(&wbin[wq + lc][32 + lg * 8]);
#pragma unroll
        for (int dt = 0; dt < 4; ++dt) {
            v8s bv0 = *reinterpret_cast<const v8s*>(&Plds[dt * 16 + lc][lg * 8]);
            v8s bv1 = *reinterpret_cast<const v8s*>(&Plds[dt * 16 + lc][32 + lg * 8]);
            o[dt] = __builtin_amdgcn_mfma_f32_16x16x32_bf16(aw0, bv0, o[dt], 0, 0, 0);
            o[dt] = __builtin_amdgcn_mfma_f32_16x16x32_bf16(aw1, bv1, o[dt], 0, 0, 0);
        }
        if (!qstm) {   // rank-1 fixup for bin v=64 (register-local: rows match)
#pragma unroll
            for (int dt = 0; dt < 4; ++dt)
#pragma unroll
                for (int r = 0; r < 4; ++r)
                    o[dt][r] += e1s[r] * relv[(size_t)64 * HD + dt * 16 + lc];
        }
    }

    // write ctx f32 [b][s][h*64+d]
#pragma unroll
    for (int dt = 0; dt < 4; ++dt)
#pragma unroll
        for (int r = 0; r < 4; ++r) {
            int gq = qbase + wq + lg * 4 + r;
            ctx[((size_t)b * SS + gq) * DIM + h * HD + dt * 16 + lc] = o[dt][r];
        }
}

// ---------------------------------------------------------------------------
extern "C" void kernel_launch(void* const* d_in, const int* in_sizes, int n_in,
                              void* d_out, int out_size, void* d_ws, size_t ws_size,
                              hipStream_t stream)
{
    const float*   stok  = (const float*)d_in[0];
    const float*   stm   = (const float*)d_in[1];
    const uint8_t* mtok  = (const uint8_t*)d_in[2];
    const uint8_t* mstm  = (const uint8_t*)d_in[3];
    const float*   qkv_w = (const float*)d_in[4];
    const float*   qkv_b = (const float*)d_in[5];
    const float*   out_w = (const float*)d_in[6];
    const float*   out_b = (const float*)d_in[7];
    const float*   relk  = (const float*)d_in[8];
    const float*   relv  = (const float*)d_in[9];
    const float*   smk   = (const float*)d_in[10];
    const float*   smv   = (const float*)d_in[11];

    float* out_final = (float*)d_out;
    float* out_attn  = out_final + (size_t)BB * SS * DIM;

    const size_t SZ = (size_t)BB * HH * SS * HD;           // 5,242,880
    ushort* qb16 = (ushort*)d_ws;
    ushort* kb16 = qb16 + SZ;
    ushort* vt16 = kb16 + SZ;
    float*  ctx  = (float*)(vt16 + SZ);

    gemm_qkv<<<dim3(960), dim3(256), 0, stream>>>(stok, stm, qkv_w, qkv_b, qb16, kb16, vt16);
    attn_mfma<<<dim3(1280), dim3(256), 0, stream>>>(qb16, kb16, vt16, mtok, mstm,
                                                    relk, relv, smk, smv, out_attn, ctx);
    gemm_out<<<dim3(320), dim3(256), 0, stream>>>(ctx, out_w, out_b, out_final);
}

// Round 4
// 503.022 us; speedup vs baseline: 3.5742x; 1.4878x over previous
//
#include <hip/hip_runtime.h>
#include <stdint.h>

// Problem constants
#define BB    8
#define HH    16
#define SS    640
#define STOK  512
#define STMN  128
#define HD    64
#define DIM   1024
#define NEGINF (-1e18f)

typedef short v8s __attribute__((ext_vector_type(8)));
typedef float v4f __attribute__((ext_vector_type(4)));

static __device__ __forceinline__ ushort f2b(float f) {
    union { float f; uint32_t u; } x; x.f = f;
    uint32_t u = (x.u + 0x7FFFu + ((x.u >> 16) & 1u)) >> 16;
    return (ushort)u;
}
static __device__ __forceinline__ float b2f(ushort h) {
    union { uint32_t u; float f; } x; x.u = ((uint32_t)h) << 16;
    return x.f;
}

// ---------------------------------------------------------------------------
// Kernel A0: convert x (stok||stm, [5120][1024]) and qkv_w ([3072][1024])
// to bf16.  Pure streaming, float4 -> ushort4.
// ---------------------------------------------------------------------------
__global__ __launch_bounds__(256) void cvt_bf16(
    const float* __restrict__ stok, const float* __restrict__ stm,
    const float* __restrict__ W,
    ushort* __restrict__ xb, ushort* __restrict__ Wb)
{
    const int i = blockIdx.x * 256 + threadIdx.x;
    const int XG = 5120 * 256;                      // float4-groups in x
    float4 v; ushort* dst;
    if (i < XG) {
        int row = i >> 8, g = i & 255;
        int b = row / SS, s = row % SS;
        const float* src = (s < STOK)
            ? stok + ((size_t)b * STOK + s) * DIM
            : stm  + ((size_t)b * STMN + (s - STOK)) * DIM;
        v = *reinterpret_cast<const float4*>(src + g * 4);
        dst = xb + (size_t)row * DIM + g * 4;
    } else {
        int j = i - XG;
        int row = j >> 8, g = j & 255;
        v = *reinterpret_cast<const float4*>(W + (size_t)row * DIM + g * 4);
        dst = Wb + (size_t)row * DIM + g * 4;
    }
    ushort4 o;
    o.x = f2b(v.x); o.y = f2b(v.y); o.z = f2b(v.z); o.w = f2b(v.w);
    *reinterpret_cast<ushort4*>(dst) = o;
}

// ---------------------------------------------------------------------------
// Kernel A: QKV projection via MFMA, barrier-free direct-global fragments.
// Block = 128x128 output tile; 4 waves (2x2), each 64x64 = 4x4 fragments.
// Epilogue: bf16 q[bh][s][d] (pre-scaled 1/8), k[bh][s][d], vT[bh][d][s].
// ---------------------------------------------------------------------------
__global__ __launch_bounds__(256, 4) void gemm_qkv_mfma(
    const ushort* __restrict__ xb, const ushort* __restrict__ Wb,
    const float* __restrict__ bias,
    ushort* __restrict__ qb, ushort* __restrict__ kb, ushort* __restrict__ vtb)
{
    const int t = threadIdx.x, lane = t & 63, w = t >> 6;
    // XCD-chunked swizzle (960 % 8 == 0 -> bijective), nt-major ordering:
    // each XCD works on 3 consecutive n-panels (W rows stay L2-resident).
    const int swz = ((blockIdx.x & 7) * 120) + (blockIdx.x >> 3);
    const int nt = swz / 40, mt = swz % 40;
    const int mb = mt * 128, nb = nt * 128;
    const int wm = (w >> 1) * 64, wn = (w & 1) * 64;
    const int lg = lane >> 4, lc = lane & 15;

    const ushort* pA[4];
    const ushort* pB[4];
#pragma unroll
    for (int i = 0; i < 4; ++i) {
        pA[i] = xb + (size_t)(mb + wm + i * 16 + lc) * DIM + lg * 8;
        pB[i] = Wb + (size_t)(nb + wn + i * 16 + lc) * DIM + lg * 8;
    }

    v4f acc[4][4];
#pragma unroll
    for (int i = 0; i < 4; ++i)
#pragma unroll
        for (int j = 0; j < 4; ++j) acc[i][j] = (v4f){0.f, 0.f, 0.f, 0.f};

#pragma unroll 2
    for (int kt = 0; kt < 32; ++kt) {
        const int ko = kt * 32;
        v8s af[4], bf[4];
#pragma unroll
        for (int i = 0; i < 4; ++i) af[i] = *reinterpret_cast<const v8s*>(pA[i] + ko);
#pragma unroll
        for (int i = 0; i < 4; ++i) bf[i] = *reinterpret_cast<const v8s*>(pB[i] + ko);
#pragma unroll
        for (int i = 0; i < 4; ++i)
#pragma unroll
            for (int j = 0; j < 4; ++j)
                acc[i][j] = __builtin_amdgcn_mfma_f32_16x16x32_bf16(af[i], bf[j], acc[i][j], 0, 0, 0);
    }

    const int nregion = nb >> 10;                  // 0=q 1=k 2=v (tile within one region)
    if (nregion < 2) {
        ushort* dst = nregion ? kb : qb;
        const float scale = nregion ? 1.0f : 0.125f;
#pragma unroll
        for (int j = 0; j < 4; ++j) {
            int n = nb + wn + j * 16 + lc;
            int nn = n & 1023, h = nn >> 6, d = nn & 63;
            float bi = bias[n];
#pragma unroll
            for (int i = 0; i < 4; ++i) {
                int m0 = mb + wm + i * 16 + lg * 4;
                int b = m0 / SS, s0 = m0 % SS;
                size_t base = (((size_t)b * HH + h) * SS + s0) * HD + d;
#pragma unroll
                for (int r = 0; r < 4; ++r)
                    dst[base + (size_t)r * HD] = f2b((acc[i][j][r] + bi) * scale);
            }
        }
    } else {
#pragma unroll
        for (int j = 0; j < 4; ++j) {
            int n = nb + wn + j * 16 + lc;
            int nn = n & 1023, h = nn >> 6, d = nn & 63;
            float bi = bias[n];
#pragma unroll
            for (int i = 0; i < 4; ++i) {
                int m0 = mb + wm + i * 16 + lg * 4;   // 4 consecutive s, same b
                int b = m0 / SS, s0 = m0 % SS;
                ushort4 pk;
                pk.x = f2b(acc[i][j][0] + bi);
                pk.y = f2b(acc[i][j][1] + bi);
                pk.z = f2b(acc[i][j][2] + bi);
                pk.w = f2b(acc[i][j][3] + bi);
                *reinterpret_cast<ushort4*>(
                    &vtb[(((size_t)b * HH + h) * HD + d) * SS + s0]) = pk;
            }
        }
    }
}

// ---------------------------------------------------------------------------
// Kernel C: out projection (f32, precision-critical).  ctx @ out_w.T + out_b
// ---------------------------------------------------------------------------
__global__ __launch_bounds__(256) void gemm_out(
    const float* __restrict__ X, const float* __restrict__ W,
    const float* __restrict__ bias, float* __restrict__ out)
{
    __shared__ float As[8][128];
    __shared__ float Bs[8][128];
    const int t  = threadIdx.x;
    const int mt = blockIdx.x / 8, nt = blockIdx.x % 8;
    const int mb = mt * 128, nb = nt * 128;
    const int lr = t >> 1, lk = (t & 1) * 4;
    const float* ald = X + (size_t)(mb + lr) * DIM + lk;
    const float* bld = W + (size_t)(nb + lr) * DIM + lk;
    const int ty = t >> 4, tx = t & 15;

    float acc[8][8];
#pragma unroll
    for (int i = 0; i < 8; ++i)
#pragma unroll
        for (int j = 0; j < 8; ++j) acc[i][j] = 0.f;

    for (int k0 = 0; k0 < DIM; k0 += 8) {
        float4 av = *reinterpret_cast<const float4*>(ald + k0);
        float4 bv = *reinterpret_cast<const float4*>(bld + k0);
        __syncthreads();
        As[lk + 0][lr] = av.x; As[lk + 1][lr] = av.y;
        As[lk + 2][lr] = av.z; As[lk + 3][lr] = av.w;
        Bs[lk + 0][lr] = bv.x; Bs[lk + 1][lr] = bv.y;
        Bs[lk + 2][lr] = bv.z; Bs[lk + 3][lr] = bv.w;
        __syncthreads();
#pragma unroll
        for (int kk = 0; kk < 8; ++kk) {
            float a[8], bbv[8];
            *reinterpret_cast<float4*>(a)     = *reinterpret_cast<float4*>(&As[kk][ty * 8]);
            *reinterpret_cast<float4*>(a + 4) = *reinterpret_cast<float4*>(&As[kk][ty * 8 + 4]);
            *reinterpret_cast<float4*>(bbv)     = *reinterpret_cast<float4*>(&Bs[kk][tx * 4]);
            *reinterpret_cast<float4*>(bbv + 4) = *reinterpret_cast<float4*>(&Bs[kk][64 + tx * 4]);
#pragma unroll
            for (int i = 0; i < 8; ++i)
#pragma unroll
                for (int j = 0; j < 8; ++j)
                    acc[i][j] = fmaf(a[i], bbv[j], acc[i][j]);
        }
    }
#pragma unroll
    for (int j = 0; j < 8; ++j) {
        int n = nb + (j < 4 ? tx * 4 + j : 64 + tx * 4 + (j - 4));
        float bia = bias[n];
#pragma unroll
        for (int i = 0; i < 8; ++i) {
            int m = mb + ty * 8 + i;
            out[(size_t)m * DIM + n] = acc[i][j] + bia;
        }
    }
}

// ---------------------------------------------------------------------------
// Kernel B: barrier-free MFMA attention.  Block = (b,h) x 64 q-rows; 4 waves
// x 16 rows, fully wave-independent (LDS row-partitioned).  K/V/Q fragments
// read directly from global (L1/L2-served).  Two sweeps: (1) exp-sums,
// (2) probs + attn write + PV + bin.  Rel-v = one extra MFMA tile.
// ---------------------------------------------------------------------------
__global__ __launch_bounds__(256, 4) void attn_mfma(
    const ushort* __restrict__ qb, const ushort* __restrict__ kb,
    const ushort* __restrict__ vtb,
    const uint8_t* __restrict__ mtok, const uint8_t* __restrict__ mstm,
    const float* __restrict__ relk, const float* __restrict__ relv,
    const float* __restrict__ smk,  const float* __restrict__ smv,
    float* __restrict__ attn_out, float* __restrict__ ctx)
{
    __shared__ ushort qrel[64][72];
    __shared__ ushort Plds[64][72];
    __shared__ ushort wbin[64][72];

    const int t    = threadIdx.x;
    const int lane = t & 63, w = t >> 6;
    const int swz  = ((blockIdx.x & 7) * 160) + (blockIdx.x >> 3);  // XCD-contiguous
    const int qt = swz % 10, bh = swz / 10;
    const int b = bh >> 4, h = bh & 15;
    const int qbase = qt * 64;
    const bool qstm = (qt >= 8);
    const size_t bhoff = (size_t)bh * (SS * HD);
    const int wq = w * 16, lg = lane >> 4, lc = lane & 15;
    const int RR = qstm ? 16 : 32;
    const int NV = qstm ? 33 : 65;
    const float* tabk = qstm ? smk : relk;

    // zero this wave's wbin rows (own rows only -> no barrier needed)
    for (int i = lane; i < 16 * 36; i += 64) {
        int r = i / 36, c = i - r * 36;
        *reinterpret_cast<uint32_t*>(&wbin[wq + r][c * 2]) = 0u;
    }

    // stm blocks: zero attn cols 0..511 (scores are -inf there)
    if (qstm) {
        float4 z = make_float4(0.f, 0.f, 0.f, 0.f);
        float* dst = attn_out + ((size_t)bh * SS + qbase) * SS;
        for (int idx = t; idx < 64 * 128; idx += 256) {
            int r = idx >> 7, c4 = idx & 127;
            *reinterpret_cast<float4*>(&dst[(size_t)r * SS + c4 * 4]) = z;
        }
    }

    // Q A-fragments straight from global (row = qbase+wq+lc)
    const int qrow = qbase + wq + lc;
    v8s aq0 = *reinterpret_cast<const v8s*>(&qb[bhoff + (size_t)qrow * HD + lg * 8]);
    v8s aq1 = *reinterpret_cast<const v8s*>(&qb[bhoff + (size_t)qrow * HD + 32 + lg * 8]);

    // qrel[i][v] = q_i . rel_emb_k[v] via MFMA (wave's own 16 rows)
    {
        const int ndt = qstm ? 2 : 4;
        for (int dt = 0; dt < ndt; ++dt) {
            const float* rp = tabk + (size_t)(dt * 16 + lc) * HD;
            v8s bk0, bk1;
#pragma unroll
            for (int j = 0; j < 8; ++j) {
                bk0[j] = (short)f2b(rp[lg * 8 + j]);
                bk1[j] = (short)f2b(rp[32 + lg * 8 + j]);
            }
            v4f c4 = {0.f, 0.f, 0.f, 0.f};
            c4 = __builtin_amdgcn_mfma_f32_16x16x32_bf16(aq0, bk0, c4, 0, 0, 0);
            c4 = __builtin_amdgcn_mfma_f32_16x16x32_bf16(aq1, bk1, c4, 0, 0, 0);
#pragma unroll
            for (int r = 0; r < 4; ++r)
                qrel[wq + lg * 4 + r][dt * 16 + lc] = f2b(c4[r]);
        }
        // last column v = NV-1 (row NV-1 of table), scalar partial + shfl
        const float* rp = tabk + (size_t)(NV - 1) * HD;
        float part = 0.f;
#pragma unroll
        for (int j = 0; j < 8; ++j) {
            part += b2f((ushort)aq0[j]) * rp[lg * 8 + j];
            part += b2f((ushort)aq1[j]) * rp[32 + lg * 8 + j];
        }
        part += __shfl_xor(part, 16);
        part += __shfl_xor(part, 32);
        if (lg == 0) qrel[wq + lc][NV - 1] = f2b(part);
    }

    const int tile0 = qstm ? 8 : 0;
    float lsum[4] = {0.f, 0.f, 0.f, 0.f};

    // ---- sweep 1: exp-sums (K-frags from global, no barriers) ----
    for (int kt = tile0; kt < 10; ++kt) {
        const ushort* kbase = kb + bhoff + (size_t)(kt * 64) * HD;
        const bool dorel = qstm || (kt < 8);
#pragma unroll
        for (int sub = 0; sub < 4; ++sub) {
            v8s bk0 = *reinterpret_cast<const v8s*>(&kbase[(sub * 16 + lc) * HD + lg * 8]);
            v8s bk1 = *reinterpret_cast<const v8s*>(&kbase[(sub * 16 + lc) * HD + 32 + lg * 8]);
            v4f c4 = {0.f, 0.f, 0.f, 0.f};
            c4 = __builtin_amdgcn_mfma_f32_16x16x32_bf16(aq0, bk0, c4, 0, 0, 0);
            c4 = __builtin_amdgcn_mfma_f32_16x16x32_bf16(aq1, bk1, c4, 0, 0, 0);
            int kg = kt * 64 + sub * 16 + lc;
            uint8_t mk = (kg < STOK) ? mtok[b * STOK + kg] : mstm[b * STMN + kg - STOK];
#pragma unroll
            for (int r = 0; r < 4; ++r) {
                int lq = wq + lg * 4 + r;
                float val = c4[r];
                if (dorel) {
                    int dlt = kg - (qbase + lq);
                    dlt = dlt < -RR ? -RR : (dlt > RR ? RR : dlt);
                    val += b2f(qrel[lq][dlt + RR]);
                }
                if (mk) val = NEGINF;
                lsum[r] += __expf(val);
            }
        }
    }

    float invl[4];
#pragma unroll
    for (int r = 0; r < 4; ++r) {
        float s = lsum[r];
        s += __shfl_xor(s, 1); s += __shfl_xor(s, 2);
        s += __shfl_xor(s, 4); s += __shfl_xor(s, 8);
        invl[r] = 1.f / s;
    }

    v4f o[4];
#pragma unroll
    for (int dt = 0; dt < 4; ++dt) o[dt] = (v4f){0.f, 0.f, 0.f, 0.f};
    float e0l[4] = {0.f, 0.f, 0.f, 0.f};
    float e1l[4] = {0.f, 0.f, 0.f, 0.f};
    float* arow = attn_out + ((size_t)bh * SS + qbase) * SS;

    // ---- sweep 2: probs + attn write + bins + PV (no barriers) ----
    for (int kt = tile0; kt < 10; ++kt) {
        const ushort* kbase = kb + bhoff + (size_t)(kt * 64) * HD;
        const bool dorel = qstm || (kt < 8);
#pragma unroll
        for (int sub = 0; sub < 4; ++sub) {
            v8s bk0 = *reinterpret_cast<const v8s*>(&kbase[(sub * 16 + lc) * HD + lg * 8]);
            v8s bk1 = *reinterpret_cast<const v8s*>(&kbase[(sub * 16 + lc) * HD + 32 + lg * 8]);
            v4f c4 = {0.f, 0.f, 0.f, 0.f};
            c4 = __builtin_amdgcn_mfma_f32_16x16x32_bf16(aq0, bk0, c4, 0, 0, 0);
            c4 = __builtin_amdgcn_mfma_f32_16x16x32_bf16(aq1, bk1, c4, 0, 0, 0);
            int kg = kt * 64 + sub * 16 + lc;
            uint8_t mk = (kg < STOK) ? mtok[b * STOK + kg] : mstm[b * STMN + kg - STOK];
#pragma unroll
            for (int r = 0; r < 4; ++r) {
                int lq = wq + lg * 4 + r;
                int dlt = kg - (qbase + lq);
                int dc = dlt < -RR ? -RR : (dlt > RR ? RR : dlt);
                float val = c4[r];
                if (dorel) val += b2f(qrel[lq][dc + RR]);
                if (mk) val = NEGINF;
                float p = __expf(val) * invl[r];
                arow[(size_t)lq * SS + kg] = p;
                Plds[lq][sub * 16 + lc] = f2b(p);
                if (dorel) {
                    if (dlt > -RR && dlt < RR) wbin[lq][dlt + RR] = f2b(p);
                    else if (dlt <= -RR) e0l[r] += p;
                    else e1l[r] += p;
                }
            }
        }
        // PV for this tile (A from own Plds rows, B = V^T frags from global)
        v8s ap0 = *reinterpret_cast<const v8s*>(&Plds[wq + lc][lg * 8]);
        v8s ap1 = *reinterpret_cast<const v8s*>(&Plds[wq + lc][32 + lg * 8]);
        const ushort* vbase = vtb + bhoff + kt * 64;
#pragma unroll
        for (int dt = 0; dt < 4; ++dt) {
            v8s bv0 = *reinterpret_cast<const v8s*>(&vbase[(size_t)(dt * 16 + lc) * SS + lg * 8]);
            v8s bv1 = *reinterpret_cast<const v8s*>(&vbase[(size_t)(dt * 16 + lc) * SS + 32 + lg * 8]);
            o[dt] = __builtin_amdgcn_mfma_f32_16x16x32_bf16(ap0, bv0, o[dt], 0, 0, 0);
            o[dt] = __builtin_amdgcn_mfma_f32_16x16x32_bf16(ap1, bv1, o[dt], 0, 0, 0);
        }
    }

    // edge-bin reduce (over the 16 col-lanes) + write; e1 kept for stok fixup
    float e1s[4];
#pragma unroll
    for (int r = 0; r < 4; ++r) {
        float s0 = e0l[r], s1 = e1l[r];
        s0 += __shfl_xor(s0, 1); s0 += __shfl_xor(s0, 2);
        s0 += __shfl_xor(s0, 4); s0 += __shfl_xor(s0, 8);
        s1 += __shfl_xor(s1, 1); s1 += __shfl_xor(s1, 2);
        s1 += __shfl_xor(s1, 4); s1 += __shfl_xor(s1, 8);
        e1s[r] = s1;
        if (lc == 0) {
            wbin[wq + lg * 4 + r][0] = f2b(s0);
            if (qstm) wbin[wq + lg * 4 + r][32] = f2b(s1);
        }
    }

    // ---- rel-v virtual tile: stage relv^T into Plds (cross-wave) ----
    __syncthreads();
    {
        const float* tabv = qstm ? smv : relv;
        for (int idx = t; idx < 64 * 64; idx += 256) {
            int d = idx >> 6, v = idx & 63;
            float f = (v < NV) ? tabv[(size_t)v * HD + d] : 0.f;
            Plds[d][v] = f2b(f);
        }
    }
    __syncthreads();
    {
        v8s aw0 = *reinterpret_cast<const v8s*>(&wbin[wq + lc][lg * 8]);
        v8s aw1 = *reinterpret_cast<const v8s*>(&wbin[wq + lc][32 + lg * 8]);
#pragma unroll
        for (int dt = 0; dt < 4; ++dt) {
            v8s bv0 = *reinterpret_cast<const v8s*>(&Plds[dt * 16 + lc][lg * 8]);
            v8s bv1 = *reinterpret_cast<const v8s*>(&Plds[dt * 16 + lc][32 + lg * 8]);
            o[dt] = __builtin_amdgcn_mfma_f32_16x16x32_bf16(aw0, bv0, o[dt], 0, 0, 0);
            o[dt] = __builtin_amdgcn_mfma_f32_16x16x32_bf16(aw1, bv1, o[dt], 0, 0, 0);
        }
        if (!qstm) {   // rank-1 fixup for bin v=64 (register-local: rows match)
#pragma unroll
            for (int dt = 0; dt < 4; ++dt)
#pragma unroll
                for (int r = 0; r < 4; ++r)
                    o[dt][r] += e1s[r] * relv[(size_t)64 * HD + dt * 16 + lc];
        }
    }

    // write ctx f32 [b][s][h*64+d]
#pragma unroll
    for (int dt = 0; dt < 4; ++dt)
#pragma unroll
        for (int r = 0; r < 4; ++r) {
            int gq = qbase + wq + lg * 4 + r;
            ctx[((size_t)b * SS + gq) * DIM + h * HD + dt * 16 + lc] = o[dt][r];
        }
}

// ---------------------------------------------------------------------------
extern "C" void kernel_launch(void* const* d_in, const int* in_sizes, int n_in,
                              void* d_out, int out_size, void* d_ws, size_t ws_size,
                              hipStream_t stream)
{
    const float*   stok  = (const float*)d_in[0];
    const float*   stm   = (const float*)d_in[1];
    const uint8_t* mtok  = (const uint8_t*)d_in[2];
    const uint8_t* mstm  = (const uint8_t*)d_in[3];
    const float*   qkv_w = (const float*)d_in[4];
    const float*   qkv_b = (const float*)d_in[5];
    const float*   out_w = (const float*)d_in[6];
    const float*   out_b = (const float*)d_in[7];
    const float*   relk  = (const float*)d_in[8];
    const float*   relv  = (const float*)d_in[9];
    const float*   smk   = (const float*)d_in[10];
    const float*   smv   = (const float*)d_in[11];

    float* out_final = (float*)d_out;
    float* out_attn  = out_final + (size_t)BB * SS * DIM;

    const size_t SZ = (size_t)BB * HH * SS * HD;           // 5,242,880
    ushort* qb16 = (ushort*)d_ws;
    ushort* kb16 = qb16 + SZ;
    ushort* vt16 = kb16 + SZ;
    ushort* xb16 = vt16 + SZ;                              // 5,242,880 ushorts
    ushort* wb16 = xb16 + SZ;                              // 3,145,728 ushorts
    float*  ctx  = (float*)(wb16 + (size_t)3 * DIM * DIM); // f32, 4B aligned

    cvt_bf16<<<dim3(8192), dim3(256), 0, stream>>>(stok, stm, qkv_w, xb16, wb16);
    gemm_qkv_mfma<<<dim3(960), dim3(256), 0, stream>>>(xb16, wb16, qkv_b, qb16, kb16, vt16);
    attn_mfma<<<dim3(1280), dim3(256), 0, stream>>>(qb16, kb16, vt16, mtok, mstm,
                                                    relk, relv, smk, smv, out_attn, ctx);
    gemm_out<<<dim3(320), dim3(256), 0, stream>>>(ctx, out_w, out_b, out_final);
}